// Round 15
// baseline (131.043 us; speedup 1.0000x reference)
//
#include <hip/hip_runtime.h>
#include <hip/hip_bf16.h>

// DiffRenderer v14: TWO-PHASE split to de-interleave HBM read/write streams.
// Ledger: nt stores +14us (confirmed L2 write-allocate thrash); nt loads
// -78us (reverted; L1 cross-lane reuse is load-bearing); all instruction-
// level ablations null. Residual symptom: write stream at 5.0 TB/s vs 6.85
// pure-write fill = fine-grained HBM direction turnaround from interleaved
// softmax reads. Phase 1: softmax -> packed bf16 probs (42.5MB, cached
// stores -> L3). Phase 2: probs (L3) -> render -> nt stores; HBM sees a
// ~pure write stream. Fallback to mono-kernel v11b if ws_size too small.
#define ROWS 384
#define COLS 768
#define NCH  69
#define CH   28
#define CW   14
#define KP   96             // font K padded to 3 k-steps of 32 (zeros past 68)
#define IMG_W 10752
#define ROW_U 72            // prob-row stride in ushorts (144B; k69..71 = 0)
#define ROW_U_F 104         // fallback kernel's stride
#define FH_ELems (CH * 16 * KP)
#define PROB_OFF 131072
#define PROBS_BYTES (294912ull * ROW_U * 2)

typedef __attribute__((ext_vector_type(8))) short bfrag;   // 8 bf16 (4 VGPR)
typedef __attribute__((ext_vector_type(4))) float f32x4;   // C/D frag / stores

__device__ __forceinline__ unsigned bf16bits(float x) {
    unsigned b = __float_as_uint(x);
    b += 0x7FFFu + ((b >> 16) & 1u);   // RTNE
    return b >> 16;
}

// ---- font (69,28,14) f32 -> Fh[28][16][96] bf16 (zero-padded) ----
__global__ __launch_bounds__(256)
void font_prep(const float* __restrict__ font, unsigned short* __restrict__ Fh) {
    int idx = blockIdx.x * 256 + threadIdx.x;        // 43008
    if (idx >= FH_ELems) return;
    int k  = idx % KP;
    int hw = idx / KP;
    int w  = hw % 16, h = hw / 16;
    float v = (w < CW && k < NCH) ? font[k * (CH * CW) + h * CW + w] : 0.f;
    Fh[idx] = (unsigned short)bf16bits(v);
}

// ---- phase 1: softmax -> packed bf16 prob rows (72 u16/cell) ----
__global__ __launch_bounds__(256)
void softmax_probs(const float* __restrict__ logits,
                   unsigned short* __restrict__ probs) {
    const int cell = blockIdx.x * 256 + threadIdx.x;   // 294912
    const float* lp = logits + (size_t)cell * NCH;
    float e[NCH];
    float m = -INFINITY;
#pragma unroll
    for (int n = 0; n < NCH; ++n) { e[n] = lp[n]; m = fmaxf(m, e[n]); }
    float s = 0.f;
#pragma unroll
    for (int n = 0; n < NCH; ++n) { e[n] = __expf(e[n] - m); s += e[n]; }
    const float inv = 1.f / s;

    unsigned pk[ROW_U / 2];
#pragma unroll
    for (int i = 0; i < 34; ++i)
        pk[i] = bf16bits(e[2 * i] * inv) | (bf16bits(e[2 * i + 1] * inv) << 16);
    pk[34] = bf16bits(e[68] * inv);    // k68 | 0
    pk[35] = 0;                        // k70,71 = 0

    // 144B contiguous per lane; cached stores (want L2/L3 residency)
    uint4* dst = (uint4*)(probs + (size_t)cell * ROW_U);
#pragma unroll
    for (int i = 0; i < 9; ++i)
        dst[i] = make_uint4(pk[4 * i], pk[4 * i + 1], pk[4 * i + 2], pk[4 * i + 3]);
}

// ---- phase 2: probs -> MFMA render -> nt-store assemble (no softmax) ----
__global__ __launch_bounds__(128, 3)
void render_v14(const unsigned short* __restrict__ probs,   // (294912,72) bf16
                const unsigned short* __restrict__ Fh,      // (28,16,96) bf16
                float* __restrict__ out)                    // (10752,10752) f32
{
    __shared__ __align__(16) unsigned short smem[2][64 * ROW_U]; // 18432 B

    const int tid  = threadIdx.x;
    const int lane = tid & 63;
    const int wv   = tid >> 6;
    const int cell = blockIdx.x * 128 + tid;
    const int r    = blockIdx.x / 6;                 // cell row (6 blocks/row)
    const int cb   = (blockIdx.x % 6) * 128;         // first cell col of block

    // own prob row (144B) -> regs -> per-wave LDS
    const bfrag* gp = (const bfrag*)(probs + (size_t)cell * ROW_U);
    bfrag tmp[9];
#pragma unroll
    for (int i = 0; i < 9; ++i) tmp[i] = gp[i];
    bfrag* lrow = (bfrag*)&smem[wv][(size_t)lane * ROW_U];
#pragma unroll
    for (int i = 0; i < 9; ++i) lrow[i] = tmp[i];

    // ---- A-frags (4 M-tiles x 3 k-steps), ROW_U=72 shared-ks2 trick ----
    const int w15   = lane & 15;
    const int g     = lane >> 4;
    const int kgrp  = g * 8;
    const int crow4 = g * 4;
    bfrag a[4][3];
#pragma unroll
    for (int mt = 0; mt < 4; ++mt) {
        const size_t base = (size_t)(mt * 16 + w15) * ROW_U;
        a[mt][0] = *(const bfrag*)&smem[wv][base + kgrp];
        a[mt][1] = *(const bfrag*)&smem[wv][base + 32 + kgrp];
        // all groups read k64..71; font slices k>=72 (g>=1) are zero rows
        a[mt][2] = *(const bfrag*)&smem[wv][base + 64];
    }

    // prob buffer dead -> reuse as f32 stage (2 rows x 896 = 7168B <= 9216B)
    float* stage = (float*)&smem[wv][0];

    // ---- h loop: TWO image rows per iteration, double-buffered B ----
    const unsigned short* fb = Fh + (size_t)w15 * KP + kgrp;
    bfrag bcur[2][3], bnxt[2][3];
#pragma unroll
    for (int hh = 0; hh < 2; ++hh)
#pragma unroll
        for (int ks = 0; ks < 3; ++ks)
            bcur[hh][ks] = *(const bfrag*)(fb + (size_t)(hh * 16) * KP + ks * 32);

#pragma unroll 1
    for (int h2 = 0; h2 < CH / 2; ++h2) {
        const int h = 2 * h2;
        if (h2 + 1 < CH / 2) {
            const unsigned short* fn = fb + (size_t)((h + 2) * 16) * KP;
#pragma unroll
            for (int hh = 0; hh < 2; ++hh)
#pragma unroll
                for (int ks = 0; ks < 3; ++ks)
                    bnxt[hh][ks] = *(const bfrag*)(fn + (size_t)(hh * 16) * KP + ks * 32);
        }

        f32x4 acc[2][4];
#pragma unroll
        for (int hh = 0; hh < 2; ++hh)
#pragma unroll
            for (int mt = 0; mt < 4; ++mt)
                acc[hh][mt] = f32x4{0, 0, 0, 0};
#pragma unroll
        for (int hh = 0; hh < 2; ++hh)
#pragma unroll
            for (int mt = 0; mt < 4; ++mt)
#pragma unroll
                for (int ks = 0; ks < 3; ++ks)
                    acc[hh][mt] = __builtin_amdgcn_mfma_f32_16x16x32_bf16(
                        a[mt][ks], bcur[hh][ks], acc[hh][mt], 0, 0, 0);

        if (w15 < CW) {
#pragma unroll
            for (int hh = 0; hh < 2; ++hh)
#pragma unroll
                for (int mt = 0; mt < 4; ++mt)
#pragma unroll
                    for (int j = 0; j < 4; ++j)
                        stage[hh * 896 + (mt * 16 + crow4 + j) * CW + w15] = acc[hh][mt][j];
        }

#pragma unroll
        for (int hh = 0; hh < 2; ++hh) {
            f32x4* o4 = (f32x4*)(out + (size_t)(r * CH + h + hh) * IMG_W
                                     + (size_t)(cb + wv * 64) * CW);
            const f32x4* s4 = (const f32x4*)(stage + hh * 896);
#pragma unroll
            for (int i = 0; i < 4; ++i) {
                const int idx = i * 64 + lane;
                if (idx < 224) __builtin_nontemporal_store(s4[idx], &o4[idx]);
            }
        }

#pragma unroll
        for (int hh = 0; hh < 2; ++hh)
#pragma unroll
            for (int ks = 0; ks < 3; ++ks)
                bcur[hh][ks] = bnxt[hh][ks];
    }
}

// ---- fallback mono-kernel (v11b verbatim, proven 107.9us) ----
__global__ __launch_bounds__(128, 3)
void diffrender_mono(const float* __restrict__ logits,
                     const unsigned short* __restrict__ Fh,
                     float* __restrict__ out)
{
    __shared__ __align__(16) unsigned short smem[2][64 * ROW_U_F];

    const int tid  = threadIdx.x;
    const int lane = tid & 63;
    const int wv   = tid >> 6;
    const int cell = blockIdx.x * 128 + tid;
    const int r    = blockIdx.x / 6;
    const int cb   = (blockIdx.x % 6) * 128;

    const float* lp = logits + (size_t)cell * NCH;
    float e[NCH];
    float m = -INFINITY;
#pragma unroll
    for (int n = 0; n < NCH; ++n) { e[n] = lp[n]; m = fmaxf(m, e[n]); }
    float s = 0.f;
#pragma unroll
    for (int n = 0; n < NCH; ++n) { e[n] = __expf(e[n] - m); s += e[n]; }
    const float inv = 1.f / s;

    unsigned* prow = (unsigned*)&smem[wv][(size_t)lane * ROW_U_F];
#pragma unroll
    for (int i = 0; i < 34; ++i)
        prow[i] = bf16bits(e[2 * i] * inv) | (bf16bits(e[2 * i + 1] * inv) << 16);
    prow[34] = bf16bits(e[68] * inv);
#pragma unroll
    for (int i = 35; i < 48; ++i) prow[i] = 0;

    const int w15   = lane & 15;
    const int kgrp  = (lane >> 4) * 8;
    const int crow4 = (lane >> 4) * 4;
    bfrag a[4][3];
#pragma unroll
    for (int mt = 0; mt < 4; ++mt)
#pragma unroll
        for (int ks = 0; ks < 3; ++ks)
            a[mt][ks] = *(const bfrag*)&smem[wv][(size_t)(mt * 16 + w15) * ROW_U_F + ks * 32 + kgrp];

    float* stage = (float*)&smem[wv][0];

    const unsigned short* fb = Fh + (size_t)w15 * KP + kgrp;
    bfrag bcur[2][3], bnxt[2][3];
#pragma unroll
    for (int hh = 0; hh < 2; ++hh)
#pragma unroll
        for (int ks = 0; ks < 3; ++ks)
            bcur[hh][ks] = *(const bfrag*)(fb + (size_t)(hh * 16) * KP + ks * 32);

#pragma unroll 1
    for (int h2 = 0; h2 < CH / 2; ++h2) {
        const int h = 2 * h2;
        if (h2 + 1 < CH / 2) {
            const unsigned short* fn = fb + (size_t)((h + 2) * 16) * KP;
#pragma unroll
            for (int hh = 0; hh < 2; ++hh)
#pragma unroll
                for (int ks = 0; ks < 3; ++ks)
                    bnxt[hh][ks] = *(const bfrag*)(fn + (size_t)(hh * 16) * KP + ks * 32);
        }

        f32x4 acc[2][4];
#pragma unroll
        for (int hh = 0; hh < 2; ++hh)
#pragma unroll
            for (int mt = 0; mt < 4; ++mt)
                acc[hh][mt] = f32x4{0, 0, 0, 0};
#pragma unroll
        for (int hh = 0; hh < 2; ++hh)
#pragma unroll
            for (int mt = 0; mt < 4; ++mt)
#pragma unroll
                for (int ks = 0; ks < 3; ++ks)
                    acc[hh][mt] = __builtin_amdgcn_mfma_f32_16x16x32_bf16(
                        a[mt][ks], bcur[hh][ks], acc[hh][mt], 0, 0, 0);

        if (w15 < CW) {
#pragma unroll
            for (int hh = 0; hh < 2; ++hh)
#pragma unroll
                for (int mt = 0; mt < 4; ++mt)
#pragma unroll
                    for (int j = 0; j < 4; ++j)
                        stage[hh * 896 + (mt * 16 + crow4 + j) * CW + w15] = acc[hh][mt][j];
        }

#pragma unroll
        for (int hh = 0; hh < 2; ++hh) {
            f32x4* o4 = (f32x4*)(out + (size_t)(r * CH + h + hh) * IMG_W
                                     + (size_t)(cb + wv * 64) * CW);
            const f32x4* s4 = (const f32x4*)(stage + hh * 896);
#pragma unroll
            for (int i = 0; i < 4; ++i) {
                const int idx = i * 64 + lane;
                if (idx < 224) __builtin_nontemporal_store(s4[idx], &o4[idx]);
            }
        }

#pragma unroll
        for (int hh = 0; hh < 2; ++hh)
#pragma unroll
            for (int ks = 0; ks < 3; ++ks)
                bcur[hh][ks] = bnxt[hh][ks];
    }
}

extern "C" void kernel_launch(void* const* d_in, const int* in_sizes, int n_in,
                              void* d_out, int out_size, void* d_ws, size_t ws_size,
                              hipStream_t stream) {
    const float* logits = (const float*)d_in[0];   // (294912,69) f32
    const float* font   = (const float*)d_in[1];   // (69,28,14)  f32
    float* out          = (float*)d_out;           // (10752,10752) f32
    unsigned short* Fh  = (unsigned short*)d_ws;   // 86KB @ offset 0

    font_prep<<<(FH_ELems + 255) / 256, 256, 0, stream>>>(font, Fh);

    const size_t need = PROB_OFF + PROBS_BYTES;    // ~40.6 MiB
    if (ws_size >= need) {
        unsigned short* probs = (unsigned short*)((char*)d_ws + PROB_OFF);
        softmax_probs<<<(ROWS * COLS) / 256, 256, 0, stream>>>(logits, probs);
        render_v14<<<(ROWS * COLS) / 128, 128, 0, stream>>>(probs, Fh, out);
    } else {
        diffrender_mono<<<(ROWS * COLS) / 128, 128, 0, stream>>>(logits, Fh, out);
    }
}

// Round 16
// 106.586 us; speedup vs baseline: 1.2295x; 1.2295x over previous
//
#include <hip/hip_runtime.h>
#include <hip/hip_bf16.h>

// DiffRenderer v15: v11b (nt stores) + v7's global_load_lds logits staging.
// Ledger: nt stores +14us; nt loads -78 (revert); phase-split -23 (revert);
// fences/coalescing/occupancy/LDS-traffic/XCD all null. Residual model:
// write floor 67us + read 13us ~= 80us vs measured 108. Remaining lever:
// the scalar-load softmax prologue (69 dword loads/lane through L1, all
// waves simultaneously at kernel start). v7 proved coalesced chunk staging
// correct but tested it under the (now-lifted) write-throttle regime.
// Per-wave 17664B chunk via 18x global_load_lds(16B); softmax from LDS;
// probs overlay (ROW_U=72, v13 shared-ks2 trick); stage overlay; nt stores.
#define ROWS 384
#define COLS 768
#define NCH  69
#define CH   28
#define CW   14
#define KP   96             // font K padded to 3 k-steps of 32 (zeros past 68)
#define IMG_W 10752
#define ROW_U 72            // prob-row stride in ushorts (144B; k69..71 = 0)
#define CHUNK_B (64 * NCH * 4)   // 17664 B: one wave's logits chunk

typedef __attribute__((ext_vector_type(8))) short bfrag;   // 8 bf16 (4 VGPR)
typedef __attribute__((ext_vector_type(4))) float f32x4;   // C/D frag / stores

__device__ __forceinline__ unsigned bf16bits(float x) {
    unsigned b = __float_as_uint(x);
    b += 0x7FFFu + ((b >> 16) & 1u);   // RTNE
    return b >> 16;
}

__device__ __forceinline__ void gload_lds16(const void* g, void* l) {
    // per-lane global src; LDS dest = wave-uniform base + lane*16
    __builtin_amdgcn_global_load_lds(
        (const __attribute__((address_space(1))) void*)g,
        (__attribute__((address_space(3))) void*)l, 16, 0, 0);
}

// ---- kernel 1: font (69,28,14) f32 -> Fh[28][16][96] bf16 (zero-padded) ----
__global__ __launch_bounds__(256)
void font_prep(const float* __restrict__ font, unsigned short* __restrict__ Fh) {
    int idx = blockIdx.x * 256 + threadIdx.x;        // 28*16*96 = 43008
    if (idx >= CH * 16 * KP) return;
    int k  = idx % KP;
    int hw = idx / KP;
    int w  = hw % 16, h = hw / 16;
    float v = (w < CW && k < NCH) ? font[k * (CH * CW) + h * CW + w] : 0.f;
    Fh[idx] = (unsigned short)bf16bits(v);
}

// ---- kernel 2: staged softmax + MFMA blend + nt-store assemble ----
__global__ __launch_bounds__(128, 2)
void diffrender_v15(const float* __restrict__ logits,       // (294912,69) f32
                    const unsigned short* __restrict__ Fh,  // (28,16,96) bf16
                    float* __restrict__ out)                // (10752,10752) f32
{
    __shared__ __align__(16) unsigned char smem[2][CHUNK_B]; // 35.3 KB, per-wave

    const int tid  = threadIdx.x;
    const int lane = tid & 63;
    const int wv   = tid >> 6;
    const int r    = blockIdx.x / 6;                 // cell row (6 blocks/row)
    const int cb   = (blockIdx.x % 6) * 128;         // first cell col of block

    unsigned char* wch = smem[wv];

    // ---- coalesced logits -> per-wave LDS chunk [64][69] f32 ----
    const char* gbase = (const char*)logits
                      + (size_t)(blockIdx.x * 128 + wv * 64) * (NCH * 4);
#pragma unroll
    for (int i = 0; i < 18; ++i) {
        const int off = (i < 17) ? i * 1024 : (CHUNK_B - 1024);  // tail overlaps
        gload_lds16(gbase + off + lane * 16, (void*)(wch + off));
    }
    asm volatile("s_waitcnt vmcnt(0)" ::: "memory");

    // ---- softmax from own LDS row (276B stride: 2-way banks) ----
    const float* myrow = (const float*)(wch + (size_t)lane * (NCH * 4));
    float e[NCH];
    float m = -INFINITY;
#pragma unroll
    for (int n = 0; n < NCH; ++n) { e[n] = myrow[n]; m = fmaxf(m, e[n]); }
    float s = 0.f;
#pragma unroll
    for (int n = 0; n < NCH; ++n) { e[n] = __expf(e[n] - m); s += e[n]; }
    const float inv = 1.f / s;

    // ---- pack probs bf16 -> same chunk, rows of ROW_U=72 ushorts ----
    // (overlay safe: wave-lockstep, compiler keeps same-object LDS order)
    unsigned* prow = (unsigned*)(wch + (size_t)lane * (ROW_U * 2));
#pragma unroll
    for (int i = 0; i < 34; ++i)
        prow[i] = bf16bits(e[2 * i] * inv) | (bf16bits(e[2 * i + 1] * inv) << 16);
    prow[34] = bf16bits(e[68] * inv);          // k68 | 0
    prow[35] = 0;                              // k70,71 = 0

    // ---- A-frags (4 M-tiles x 3 k-steps), shared-ks2 trick ----
    const int w15   = lane & 15;
    const int g     = lane >> 4;
    const int kgrp  = g * 8;
    const int crow4 = g * 4;
    const unsigned short* pa = (const unsigned short*)wch;
    bfrag a[4][3];
#pragma unroll
    for (int mt = 0; mt < 4; ++mt) {
        const size_t base = (size_t)(mt * 16 + w15) * ROW_U;
        a[mt][0] = *(const bfrag*)&pa[base + kgrp];
        a[mt][1] = *(const bfrag*)&pa[base + 32 + kgrp];
        // all lane-groups read k64..71; font k>=69 rows are zero -> product 0
        a[mt][2] = *(const bfrag*)&pa[base + 64];
    }

    // chunk dead after frag reads -> reuse as f32 stage (2 rows x 896)
    float* stage = (float*)wch;

    // ---- h loop: TWO image rows per iteration, double-buffered B ----
    const unsigned short* fb = Fh + (size_t)w15 * KP + kgrp;
    bfrag bcur[2][3], bnxt[2][3];
#pragma unroll
    for (int hh = 0; hh < 2; ++hh)
#pragma unroll
        for (int ks = 0; ks < 3; ++ks)
            bcur[hh][ks] = *(const bfrag*)(fb + (size_t)(hh * 16) * KP + ks * 32);

#pragma unroll 1
    for (int h2 = 0; h2 < CH / 2; ++h2) {
        const int h = 2 * h2;
        if (h2 + 1 < CH / 2) {
            const unsigned short* fn = fb + (size_t)((h + 2) * 16) * KP;
#pragma unroll
            for (int hh = 0; hh < 2; ++hh)
#pragma unroll
                for (int ks = 0; ks < 3; ++ks)
                    bnxt[hh][ks] = *(const bfrag*)(fn + (size_t)(hh * 16) * KP + ks * 32);
        }

        f32x4 acc[2][4];
#pragma unroll
        for (int hh = 0; hh < 2; ++hh)
#pragma unroll
            for (int mt = 0; mt < 4; ++mt)
                acc[hh][mt] = f32x4{0, 0, 0, 0};
#pragma unroll
        for (int hh = 0; hh < 2; ++hh)
#pragma unroll
            for (int mt = 0; mt < 4; ++mt)
#pragma unroll
                for (int ks = 0; ks < 3; ++ks)
                    acc[hh][mt] = __builtin_amdgcn_mfma_f32_16x16x32_bf16(
                        a[mt][ks], bcur[hh][ks], acc[hh][mt], 0, 0, 0);

        // transpose through per-wave LDS: stage[hh][cell_local*14 + w]
        if (w15 < CW) {
#pragma unroll
            for (int hh = 0; hh < 2; ++hh)
#pragma unroll
                for (int mt = 0; mt < 4; ++mt)
#pragma unroll
                    for (int j = 0; j < 4; ++j)
                        stage[hh * 896 + (mt * 16 + crow4 + j) * CW + w15] = acc[hh][mt][j];
        }

        // coalesced NONTEMPORAL stores: per row, 224 f32x4 (4 masked insts)
#pragma unroll
        for (int hh = 0; hh < 2; ++hh) {
            f32x4* o4 = (f32x4*)(out + (size_t)(r * CH + h + hh) * IMG_W
                                     + (size_t)(cb + wv * 64) * CW);
            const f32x4* s4 = (const f32x4*)(stage + hh * 896);
#pragma unroll
            for (int i = 0; i < 4; ++i) {
                const int idx = i * 64 + lane;
                if (idx < 224) __builtin_nontemporal_store(s4[idx], &o4[idx]);
            }
        }

#pragma unroll
        for (int hh = 0; hh < 2; ++hh)
#pragma unroll
            for (int ks = 0; ks < 3; ++ks)
                bcur[hh][ks] = bnxt[hh][ks];
    }
}

extern "C" void kernel_launch(void* const* d_in, const int* in_sizes, int n_in,
                              void* d_out, int out_size, void* d_ws, size_t ws_size,
                              hipStream_t stream) {
    const float* logits = (const float*)d_in[0];   // (294912,69) f32
    const float* font   = (const float*)d_in[1];   // (69,28,14)  f32
    float* out          = (float*)d_out;           // (10752,10752) f32
    unsigned short* Fh  = (unsigned short*)d_ws;   // (28,16,96) bf16 = 86KB

    font_prep<<<(CH * 16 * KP + 255) / 256, 256, 0, stream>>>(font, Fh);

    const int blocks = (ROWS * COLS) / 128;        // 2304
    diffrender_v15<<<blocks, 128, 0, stream>>>(logits, Fh, out);
}